// Round 2
// baseline (390.277 us; speedup 1.0000x reference)
//
#include <hip/hip_runtime.h>

// LatentLinearModel: out[i] = dot(U[users[i]], V[jokes[i]]) + a[users[i]] + b[jokes[i]] + g
// K=64 floats/row = 256 B contiguous.
//
// R1: 16-lane groups, 4 rows/group, 8 independent float4 gathers in flight/lane.
// R2: dur_us 383 = 2x154us harness poison fills + ~75us kernel. 75us @6.6TB/s
// ~ 495 MB = NO-REUSE traffic: U's 268 MB/iter stream thrashes the 256 MB L3,
// evicting the high-reuse V (25.6 MB, 10.5x reuse) and a (4 MB) tables.
// Fix: U gathers are single-touch -> NON-TEMPORAL (evict-first) so V/a/b stay
// resident. Bias gathers lane-distributed + issued early (latency overlap).
// R3 (this round): compile fix only — __builtin_nontemporal_load needs a
// native clang vector type, not HIP_vector_type<float,4>. Use ext_vector_type.

constexpr int KDIM = 64;
constexpr int KV   = KDIM / 4;   // float4s per row = 16
constexpr int RPG  = 4;          // rows per 16-lane group

typedef float nfloat4 __attribute__((ext_vector_type(4)));  // native vec for nt builtins

__global__ __launch_bounds__(256) void latent_linear_kernel(
    const int* __restrict__ users,
    const int* __restrict__ jokes,
    const float* __restrict__ U,
    const float* __restrict__ V,
    const float* __restrict__ a,
    const float* __restrict__ b,
    const float* __restrict__ g,
    float* __restrict__ out,
    int B)
{
    const int tid  = blockIdx.x * blockDim.x + threadIdx.x;
    const int grp  = tid >> 4;          // 16-lane group id
    const int sub  = tid & 15;          // which float4 of a row
    const int base = grp * RPG;
    if (base >= B) return;

    const nfloat4* __restrict__ U4 = reinterpret_cast<const nfloat4*>(U);
    const float4*  __restrict__ V4 = reinterpret_cast<const float4*>(V);

    const float g0 = g[0];

    if (base + RPG <= B) {
        // One int4 load covers this group's 4 user/joke indices (broadcast).
        const int4 u4 = reinterpret_cast<const int4*>(users)[grp];
        const int4 j4 = reinterpret_cast<const int4*>(jokes)[grp];
        const int ui[RPG] = {u4.x, u4.y, u4.z, u4.w};
        const int ji[RPG] = {j4.x, j4.y, j4.z, j4.w};

        // Early, lane-distributed bias gathers: lane r (r<4) loads a[ui[r]],
        // lane 4+r loads b[ji[r]]. Issued BEFORE the row gathers so their
        // ~500-900cy latency overlaps. Index selected via cndmask chain, NOT
        // a runtime-indexed register array (which would spill to scratch).
        const int s3 = sub & 3;
        const int iu = (s3 == 0) ? u4.x : (s3 == 1) ? u4.y : (s3 == 2) ? u4.z : u4.w;
        const int ij = (s3 == 0) ? j4.x : (s3 == 1) ? j4.y : (s3 == 2) ? j4.z : j4.w;
        float bias = 0.0f;
        if (sub < RPG)            bias = a[iu];            // a/b stay cached
        else if (sub < 2 * RPG)   bias = b[ij];

        // 8 independent 16 B row-gathers per lane, all in flight together.
        // U: single-touch stream (268 MB/iter) -> non-temporal (nt bit),
        // don't let it evict V/a/b from L2/L3. V: 10.5x reuse -> cacheable.
        nfloat4 uu[RPG];
        float4  vv[RPG];
#pragma unroll
        for (int r = 0; r < RPG; ++r)
            uu[r] = __builtin_nontemporal_load(&U4[(size_t)ui[r] * KV + sub]);
#pragma unroll
        for (int r = 0; r < RPG; ++r)
            vv[r] = V4[(size_t)ji[r] * KV + sub];

#pragma unroll
        for (int r = 0; r < RPG; ++r) {
            float d = uu[r].x * vv[r].x + uu[r].y * vv[r].y
                    + uu[r].z * vv[r].z + uu[r].w * vv[r].w;
            d += __shfl_down(d, 8, 16);
            d += __shfl_down(d, 4, 16);
            d += __shfl_down(d, 2, 16);
            d += __shfl_down(d, 1, 16);
            const float ar = __shfl(bias, r, 16);        // a[ui[r]] from lane r
            const float br = __shfl(bias, RPG + r, 16);  // b[ji[r]] from lane 4+r
            if (sub == 0)
                __builtin_nontemporal_store(d + ar + br + g0, &out[base + r]);
        }
    } else {
        // tail (not hit for B = 1<<20, kept for generality)
        for (int r = 0; r < RPG && base + r < B; ++r) {
            const int row = base + r;
            const int uix = users[row], jix = jokes[row];
            const float4* __restrict__ U4h = reinterpret_cast<const float4*>(U);
            const float4 uu = U4h[(size_t)uix * KV + sub];
            const float4 vv = V4[(size_t)jix * KV + sub];
            float d = uu.x * vv.x + uu.y * vv.y + uu.z * vv.z + uu.w * vv.w;
            d += __shfl_down(d, 8, 16);
            d += __shfl_down(d, 4, 16);
            d += __shfl_down(d, 2, 16);
            d += __shfl_down(d, 1, 16);
            if (sub == 0)
                out[row] = d + a[uix] + b[jix] + g0;
        }
    }
}

extern "C" void kernel_launch(void* const* d_in, const int* in_sizes, int n_in,
                              void* d_out, int out_size, void* d_ws, size_t ws_size,
                              hipStream_t stream)
{
    const int*   users = (const int*)d_in[0];
    const int*   jokes = (const int*)d_in[1];
    const float* U     = (const float*)d_in[2];
    const float* V     = (const float*)d_in[3];
    const float* a     = (const float*)d_in[4];
    const float* b     = (const float*)d_in[5];
    const float* g     = (const float*)d_in[6];
    float*       out   = (float*)d_out;

    const int B = in_sizes[0];                        // 1048576 rows
    const int groups = (B + RPG - 1) / RPG;           // 16-lane groups
    const long long threads_total = (long long)groups * 16;
    const int block = 256;
    const int grid = (int)((threads_total + block - 1) / block);

    latent_linear_kernel<<<grid, block, 0, stream>>>(users, jokes, U, V, a, b, g, out, B);
}

// Round 3
// 384.861 us; speedup vs baseline: 1.0141x; 1.0141x over previous
//
#include <hip/hip_runtime.h>

// LatentLinearModel: out[i] = dot(U[users[i]], V[jokes[i]]) + a[users[i]] + b[jokes[i]] + g
// K=64 floats/row = 256 B contiguous.
//
// R1: 16-lane groups, 4 rows/group, 8 independent float4 gathers in flight/lane.
// R2/R3: nt-on-U experiment FAILED (+7us). Post-mortem: U repeats have ~250MB
// reuse distance (> L3) -> never cached, nt saved nothing and demoted the few
// short-distance hits. V reuse distance ~51MB (< 256MB L3) -> V was ALREADY
// L3-resident in R0; no thrash to fix. Kernel ~75-82us vs ~80-88us modeled
// floor (268MB compulsory U + 30MB V/a/b + ~12MB idx/out + poison-dirty
// writeback evictions) => at the memory floor; 2x154us harness fills dominate.
// R4 (this round): isolate R3's bundle — KEEP early lane-distributed bias
// gathers + nt store, REVERT nt-U (back to cached loads).
// Predict dur 390 -> ~383. If flat at 383: declare roofline.

constexpr int KDIM = 64;
constexpr int KV   = KDIM / 4;   // float4s per row = 16
constexpr int RPG  = 4;          // rows per 16-lane group

__global__ __launch_bounds__(256) void latent_linear_kernel(
    const int* __restrict__ users,
    const int* __restrict__ jokes,
    const float* __restrict__ U,
    const float* __restrict__ V,
    const float* __restrict__ a,
    const float* __restrict__ b,
    const float* __restrict__ g,
    float* __restrict__ out,
    int B)
{
    const int tid  = blockIdx.x * blockDim.x + threadIdx.x;
    const int grp  = tid >> 4;          // 16-lane group id
    const int sub  = tid & 15;          // which float4 of a row
    const int base = grp * RPG;
    if (base >= B) return;

    const float4* __restrict__ U4 = reinterpret_cast<const float4*>(U);
    const float4* __restrict__ V4 = reinterpret_cast<const float4*>(V);

    const float g0 = g[0];

    if (base + RPG <= B) {
        // One int4 load covers this group's 4 user/joke indices (broadcast).
        const int4 u4 = reinterpret_cast<const int4*>(users)[grp];
        const int4 j4 = reinterpret_cast<const int4*>(jokes)[grp];
        const int ui[RPG] = {u4.x, u4.y, u4.z, u4.w};
        const int ji[RPG] = {j4.x, j4.y, j4.z, j4.w};

        // Early, lane-distributed bias gathers: lane r (r<4) loads a[ui[r]],
        // lane 4+r loads b[ji[r]]. Issued BEFORE the row gathers so their
        // latency overlaps the row-gather latency. Index selected via cndmask
        // chain, NOT a runtime-indexed register array (scratch rule).
        const int s3 = sub & 3;
        const int iu = (s3 == 0) ? u4.x : (s3 == 1) ? u4.y : (s3 == 2) ? u4.z : u4.w;
        const int ij = (s3 == 0) ? j4.x : (s3 == 1) ? j4.y : (s3 == 2) ? j4.z : j4.w;
        float bias = 0.0f;
        if (sub < RPG)            bias = a[iu];
        else if (sub < 2 * RPG)   bias = b[ij];

        // 8 independent 16 B row-gathers per lane, all in flight together.
        // Both U and V normal cached loads (V is L3-resident by reuse
        // distance; U repeats exceed L3 but nt demotion measured -7us).
        float4 uu[RPG], vv[RPG];
#pragma unroll
        for (int r = 0; r < RPG; ++r) uu[r] = U4[(size_t)ui[r] * KV + sub];
#pragma unroll
        for (int r = 0; r < RPG; ++r) vv[r] = V4[(size_t)ji[r] * KV + sub];

#pragma unroll
        for (int r = 0; r < RPG; ++r) {
            float d = uu[r].x * vv[r].x + uu[r].y * vv[r].y
                    + uu[r].z * vv[r].z + uu[r].w * vv[r].w;
            d += __shfl_down(d, 8, 16);
            d += __shfl_down(d, 4, 16);
            d += __shfl_down(d, 2, 16);
            d += __shfl_down(d, 1, 16);
            const float ar = __shfl(bias, r, 16);        // a[ui[r]] from lane r
            const float br = __shfl(bias, RPG + r, 16);  // b[ji[r]] from lane 4+r
            if (sub == 0)
                __builtin_nontemporal_store(d + ar + br + g0, &out[base + r]);
        }
    } else {
        // tail (not hit for B = 1<<20, kept for generality)
        for (int r = 0; r < RPG && base + r < B; ++r) {
            const int row = base + r;
            const int uix = users[row], jix = jokes[row];
            const float4 uu = U4[(size_t)uix * KV + sub];
            const float4 vv = V4[(size_t)jix * KV + sub];
            float d = uu.x * vv.x + uu.y * vv.y + uu.z * vv.z + uu.w * vv.w;
            d += __shfl_down(d, 8, 16);
            d += __shfl_down(d, 4, 16);
            d += __shfl_down(d, 2, 16);
            d += __shfl_down(d, 1, 16);
            if (sub == 0)
                out[row] = d + a[uix] + b[jix] + g0;
        }
    }
}

extern "C" void kernel_launch(void* const* d_in, const int* in_sizes, int n_in,
                              void* d_out, int out_size, void* d_ws, size_t ws_size,
                              hipStream_t stream)
{
    const int*   users = (const int*)d_in[0];
    const int*   jokes = (const int*)d_in[1];
    const float* U     = (const float*)d_in[2];
    const float* V     = (const float*)d_in[3];
    const float* a     = (const float*)d_in[4];
    const float* b     = (const float*)d_in[5];
    const float* g     = (const float*)d_in[6];
    float*       out   = (float*)d_out;

    const int B = in_sizes[0];                        // 1048576 rows
    const int groups = (B + RPG - 1) / RPG;           // 16-lane groups
    const long long threads_total = (long long)groups * 16;
    const int block = 256;
    const int grid = (int)((threads_total + block - 1) / block);

    latent_linear_kernel<<<grid, block, 0, stream>>>(users, jokes, U, V, a, b, g, out, B);
}